// Round 1
// baseline (4324.342 us; speedup 1.0000x reference)
//
#include <hip/hip_runtime.h>
#include <hip/hip_bf16.h>
#include <cstdint>
#include <cstddef>

typedef short bf16x8 __attribute__((ext_vector_type(8)));
typedef float f32x4 __attribute__((ext_vector_type(4)));
typedef unsigned short u16;

static __device__ __forceinline__ u16 f2bf(float x){
  unsigned u = __float_as_uint(x);
  u += 0x7fffu + ((u >> 16) & 1u);
  return (u16)(u >> 16);
}
static __device__ __forceinline__ float bf2f(u16 h){
  return __uint_as_float(((unsigned)h) << 16);
}
static __device__ __forceinline__ float wsum(float v){
#pragma unroll
  for (int o = 32; o; o >>= 1) v += __shfl_xor(v, o, 64);
  return v;
}
static __device__ __forceinline__ float wmaxr(float v){
#pragma unroll
  for (int o = 32; o; o >>= 1) v = fmaxf(v, __shfl_xor(v, o, 64));
  return v;
}
static __device__ __forceinline__ void gload16(const u16* g, u16* l){
  __builtin_amdgcn_global_load_lds((const __attribute__((address_space(1))) void*)g,
                                   (__attribute__((address_space(3))) void*)l, 16, 0, 0);
}

// ---------------------------------------------------------------------------
// GEMM: C[M,N] = A[M,K] * Bt[N,K]^T   (A, Bt bf16 row-major, K-contiguous)
// EPI 0: C -> bf16 (no bias)
// EPI 1: C -> bf16, += bias, ReLU
// EPI 2: Cf (f32) += C + bias   (residual update, in-place)
// EPI 3: Cf (f32) = C + bias, cols guarded to < Nreal   (head)
// Batched via blockIdx.z: z -> (zb = z/Hdiv, zh = z%Hdiv), offsets s*b/s*h.
// All M,N multiples of 128; K multiple of 32.
// ---------------------------------------------------------------------------
template<int EPI>
__global__ __launch_bounds__(256)
void gemm_bt(const u16* __restrict__ A, const u16* __restrict__ B,
             u16* __restrict__ Cb, float* __restrict__ Cf, const float* __restrict__ bias,
             int K, int lda, int ldb, int ldc, int Nreal,
             int Hdiv, long sAb, long sAh, long sBb, long sBh, long sCb, long sCh)
{
  __shared__ u16 As[128*32];
  __shared__ u16 Bs[128*32];
  const int tid = threadIdx.x;
  const int z  = blockIdx.z;
  const int zb = z / Hdiv, zh = z % Hdiv;
  A += (size_t)zb*sAb + (size_t)zh*sAh;
  B += (size_t)zb*sBb + (size_t)zh*sBh;
  const size_t coff = (size_t)zb*sCb + (size_t)zh*sCh;
  const int n0 = blockIdx.x * 128, m0 = blockIdx.y * 128;
  const int w = tid >> 6, lane = tid & 63;
  const int srow = lane >> 2, scol = (lane & 3) * 8;   // staging lane map
  const int wm = (w >> 1) * 64, wn = (w & 1) * 64;     // wave -> 64x64 quadrant
  const int lr = lane & 15, lk = (lane >> 4) * 8;      // fragment lane map
  f32x4 acc[4][4] = {};
  const u16* ga = A + (size_t)(m0 + w*16 + srow) * lda + scol;
  const u16* gb = B + (size_t)(n0 + w*16 + srow) * ldb + scol;
  for (int k0 = 0; k0 < K; k0 += 32) {
    gload16(ga + k0,                  &As[w*512]);
    gload16(ga + (size_t)64*lda + k0, &As[2048 + w*512]);
    gload16(gb + k0,                  &Bs[w*512]);
    gload16(gb + (size_t)64*ldb + k0, &Bs[2048 + w*512]);
    __syncthreads();
    bf16x8 af[4], bfr[4];
#pragma unroll
    for (int m = 0; m < 4; ++m) af[m]  = *(const bf16x8*)&As[(wm + m*16 + lr)*32 + lk];
#pragma unroll
    for (int n = 0; n < 4; ++n) bfr[n] = *(const bf16x8*)&Bs[(wn + n*16 + lr)*32 + lk];
#pragma unroll
    for (int m = 0; m < 4; ++m)
#pragma unroll
      for (int n = 0; n < 4; ++n)
        acc[m][n] = __builtin_amdgcn_mfma_f32_16x16x32_bf16(af[m], bfr[n], acc[m][n], 0, 0, 0);
    __syncthreads();
  }
  const int r0 = m0 + wm + ((lane >> 4) << 2);
  const int c0 = n0 + wn + (lane & 15);
#pragma unroll
  for (int m = 0; m < 4; ++m)
#pragma unroll
    for (int n = 0; n < 4; ++n){
      const int col = c0 + n*16;
#pragma unroll
      for (int e = 0; e < 4; ++e){
        const int row = r0 + m*16 + e;
        float v = acc[m][n][e];
        if (EPI == 0){
          Cb[coff + (size_t)row*ldc + col] = f2bf(v);
        } else if (EPI == 1){
          v += bias[col];
          Cb[coff + (size_t)row*ldc + col] = f2bf(fmaxf(v, 0.f));
        } else if (EPI == 2){
          const size_t idx = coff + (size_t)row*ldc + col;
          Cf[idx] += v + bias[col];
        } else {
          if (col < Nreal) Cf[coff + (size_t)row*ldc + col] = v + bias[col];
        }
      }
    }
}

// fp32 [Kd,Nd] -> bf16 [Nout,Kd] transpose-convert (rows >= Nd zero-filled)
__global__ void transp_kernel(const float* __restrict__ in, u16* __restrict__ out,
                              int Kd, int Nd, int Nout, int Hdiv,
                              long sib, long sih, long sob, long soh)
{
  __shared__ float tile[32][33];
  const int z = blockIdx.z, zb = z / Hdiv, zh = z % Hdiv;
  in  += (size_t)zb*sib + (size_t)zh*sih;
  out += (size_t)zb*sob + (size_t)zh*soh;
  const int kb = blockIdx.x*32, nb = blockIdx.y*32;
  const int tx = threadIdx.x, ty = threadIdx.y;
#pragma unroll
  for (int j = 0; j < 32; j += 8){
    const int k = kb + ty + j, n = nb + tx;
    tile[ty+j][tx] = (k < Kd && n < Nd) ? in[(size_t)k*Nd + n] : 0.f;
  }
  __syncthreads();
#pragma unroll
  for (int j = 0; j < 32; j += 8){
    const int n = nb + ty + j, k = kb + tx;
    if (n < Nout && k < Kd) out[(size_t)n*Kd + k] = f2bf(tile[tx][ty+j]);
  }
}

// v slab of qkv [ (b*512+t)*3072 + 2048 + h*128 + d ]  ->  vT[bh][d][t]
__global__ void vtrans_kernel(const u16* __restrict__ qkv, u16* __restrict__ vT)
{
  __shared__ u16 tile[32][33];
  const int bh = blockIdx.z, b = bh >> 3, h = bh & 7;
  const int tb = blockIdx.x*32, db = blockIdx.y*32;
  const int tx = threadIdx.x, ty = threadIdx.y;
  const u16* src = qkv + (size_t)b*512*3072 + 2048 + h*128;
#pragma unroll
  for (int j = 0; j < 32; j += 8)
    tile[ty+j][tx] = src[(size_t)(tb+ty+j)*3072 + db + tx];
  __syncthreads();
  u16* dst = vT + (size_t)bh*128*512;
#pragma unroll
  for (int j = 0; j < 32; j += 8)
    dst[(size_t)(db+ty+j)*512 + tb + tx] = tile[tx][ty+j];
}

__global__ void embed_kernel(const int* __restrict__ x, const float* __restrict__ tok,
                             const float* __restrict__ pos, float* __restrict__ h)
{
  const int r = blockIdx.x;
  const int t = r & 511;
  const int id = x[r];
  const float4 a = ((const float4*)(tok + (size_t)id*1024))[threadIdx.x];
  const float4 b = ((const float4*)(pos + (size_t)t*1024))[threadIdx.x];
  float4 o; o.x=a.x+b.x; o.y=a.y+b.y; o.z=a.z+b.z; o.w=a.w+b.w;
  ((float4*)(h + (size_t)r*1024))[threadIdx.x] = o;
}

// LayerNorm over E=1024, fp32 in -> bf16 out. 256 threads, 4 elems each.
__global__ void ln_kernel(const float* __restrict__ X, const float* __restrict__ w,
                          const float* __restrict__ b, u16* __restrict__ out)
{
  const int r = blockIdx.x, tid = threadIdx.x, lane = tid & 63, wv = tid >> 6;
  const float4 v = ((const float4*)(X + (size_t)r*1024))[tid];
  __shared__ float red[8];
  float s = wsum(v.x + v.y + v.z + v.w);
  if (lane == 0) red[wv] = s;
  __syncthreads();
  const float mean = (red[0]+red[1]+red[2]+red[3]) * (1.f/1024.f);
  const float dx = v.x-mean, dy = v.y-mean, dz = v.z-mean, dw = v.w-mean;
  float q = wsum(dx*dx + dy*dy + dz*dz + dw*dw);
  if (lane == 0) red[4+wv] = q;
  __syncthreads();
  const float var = (red[4]+red[5]+red[6]+red[7]) * (1.f/1024.f);
  const float inv = rsqrtf(var + 1e-5f);
  const float4 wv4 = ((const float4*)w)[tid];
  const float4 bv4 = ((const float4*)b)[tid];
  ushort4 o;
  o.x = f2bf(dx*inv*wv4.x + bv4.x);
  o.y = f2bf(dy*inv*wv4.y + bv4.y);
  o.z = f2bf(dz*inv*wv4.z + bv4.z);
  o.w = f2bf(dw*inv*wv4.w + bv4.w);
  ((ushort4*)(out + (size_t)r*1024))[tid] = o;
}

// In-place masked causal softmax over bf16 S[bh][t][s], s in [0,512).
__global__ void softmax_kernel(u16* __restrict__ SP, const float* __restrict__ mask, float scale)
{
  const int t = blockIdx.x, bh = blockIdx.y, b = bh >> 3;
  u16* row = SP + ((size_t)bh*512 + t)*512;
  const int tid = threadIdx.x, lane = tid & 63, w = tid >> 6;
  const unsigned pr = *(const unsigned*)&row[tid*2];
  const int c0 = tid*2, c1 = c0 + 1;
  const float x0 = bf2f((u16)(pr & 0xffffu)) * scale;
  const float x1 = bf2f((u16)(pr >> 16)) * scale;
  const bool k0 = (c0 <= t) && (mask[b*512 + c0] != 0.f);
  const bool k1 = (c1 <= t) && (mask[b*512 + c1] != 0.f);
  __shared__ float red[8];
  float m = fmaxf(k0 ? x0 : -1e30f, k1 ? x1 : -1e30f);
  m = wmaxr(m);
  if (lane == 0) red[w] = m;
  __syncthreads();
  m = fmaxf(fmaxf(red[0], red[1]), fmaxf(red[2], red[3]));
  const float e0 = k0 ? __expf(x0 - m) : 0.f;
  const float e1 = k1 ? __expf(x1 - m) : 0.f;
  float s = wsum(e0 + e1);
  if (lane == 0) red[4 + w] = s;
  __syncthreads();
  s = red[4] + red[5] + red[6] + red[7];
  const float inv = s > 0.f ? 1.f / s : 0.f;
  const unsigned ow = (unsigned)f2bf(e0*inv) | ((unsigned)f2bf(e1*inv) << 16);
  *(unsigned*)&row[tid*2] = ow;
}

// Per-row online logsumexp over V=30000 fp32 logits -> nll[r] = (lse - logit[tgt]) * mask
__global__ void loss_row_kernel(const float* __restrict__ logits, const int* __restrict__ tgt,
                                const float* __restrict__ mask, float* __restrict__ nll)
{
  const int r = blockIdx.x, tid = threadIdx.x, lane = tid & 63, w = tid >> 6;
  const float4* row = (const float4*)(logits + (size_t)r*30000);
  float m = -1e30f, s = 0.f;
  for (int i = tid; i < 7500; i += 256){
    const float4 v = row[i];
    const float mx = fmaxf(fmaxf(v.x, v.y), fmaxf(v.z, v.w));
    const float M = fmaxf(m, mx);
    s = s*__expf(m - M) + __expf(v.x - M) + __expf(v.y - M) + __expf(v.z - M) + __expf(v.w - M);
    m = M;
  }
#pragma unroll
  for (int o = 32; o; o >>= 1){
    const float m2 = __shfl_xor(m, o, 64), s2 = __shfl_xor(s, o, 64);
    const float M = fmaxf(m, m2);
    s = s*__expf(m - M) + s2*__expf(m2 - M);
    m = M;
  }
  __shared__ float lm[4], ls[4];
  if (lane == 0){ lm[w] = m; ls[w] = s; }
  __syncthreads();
  if (tid == 0){
    float M = lm[0], S = ls[0];
#pragma unroll
    for (int q2 = 1; q2 < 4; ++q2){
      const float M2 = fmaxf(M, lm[q2]);
      S = S*__expf(M - M2) + ls[q2]*__expf(lm[q2] - M2);
      M = M2;
    }
    const float lse = logf(S) + M;
    const float lg = logits[(size_t)r*30000 + tgt[r]];
    nll[r] = (lse - lg) * mask[r];
  }
}

__global__ void loss_final_kernel(const float* __restrict__ nll, const float* __restrict__ mask,
                                  float* __restrict__ out)
{
  const int tid = threadIdx.x, lane = tid & 63, w = tid >> 6;
  float sn = 0.f, sm = 0.f;
  for (int i = tid; i < 4096; i += 256){ sn += nll[i]; sm += mask[i]; }
  sn = wsum(sn); sm = wsum(sm);
  __shared__ float rn[4], rm[4];
  if (lane == 0){ rn[w] = sn; rm[w] = sm; }
  __syncthreads();
  if (tid == 0) out[0] = (rn[0]+rn[1]+rn[2]+rn[3]) / (rm[0]+rm[1]+rm[2]+rm[3]);
}

extern "C" void kernel_launch(void* const* d_in, const int* in_sizes, int n_in,
                              void* d_out, int out_size, void* d_ws, size_t ws_size,
                              hipStream_t stream)
{
  (void)in_sizes; (void)n_in; (void)out_size; (void)ws_size;
  const int*   x       = (const int*)d_in[0];
  const int*   targets = (const int*)d_in[1];
  const float* mask    = (const float*)d_in[2];
  const float* tok_emb = (const float*)d_in[3];
  const float* pos_emb = (const float*)d_in[4];
  const float* Wq      = (const float*)d_in[5];
  const float* Wk      = (const float*)d_in[6];
  const float* Wv      = (const float*)d_in[7];
  const float* Wproj   = (const float*)d_in[8];
  const float* bproj   = (const float*)d_in[9];
  const float* ln1w    = (const float*)d_in[10];
  const float* ln1b    = (const float*)d_in[11];
  const float* ln2w    = (const float*)d_in[12];
  const float* ln2b    = (const float*)d_in[13];
  const float* W1      = (const float*)d_in[14];
  const float* b1      = (const float*)d_in[15];
  const float* W2      = (const float*)d_in[16];
  const float* b2      = (const float*)d_in[17];
  const float* lnfw    = (const float*)d_in[18];
  const float* lnfb    = (const float*)d_in[19];
  const float* Whead   = (const float*)d_in[20];
  const float* bhead   = (const float*)d_in[21];

  float* logits = (float*)d_out;
  float* loss   = logits + (size_t)4096*30000;

  u16* p = (u16*)d_ws;
  u16* wqkv = p; p += (size_t)8*3072*1024;   // W{q,k,v}^T packed [l][3072][1024]
  u16* wpj  = p; p += (size_t)8*1024*1024;   // Wproj^T [l][1024][1024]
  u16* w1t  = p; p += (size_t)8*4096*1024;   // W1^T [l][4096][1024]
  u16* w2t  = p; p += (size_t)8*4096*1024;   // W2^T [l][1024][4096]
  u16* whd  = p; p += (size_t)30080*1024;    // Whead^T padded [30080][1024]
  u16* xn   = p; p += (size_t)4096*1024;     // LN output bf16
  u16* qkvb = p; p += (size_t)4096*3072;     // q|k|v  [bt][3072]
  u16* vT   = p; p += (size_t)64*128*512;    // [bh][d][t]
  u16* attb = p; p += (size_t)4096*1024;     // attention concat
  u16* spff = p; p += (size_t)4096*4096;     // shared: S/P [bh][512][512] and FFN hidden
  float* hbuf = (float*)p;                   // residual stream fp32 [4096][1024]
  float* nllb = hbuf + (size_t)4096*1024;    // per-row nll

  const dim3 TB(256), TT(32, 8);

  // Weight convert+transpose (fp32 [K,N] -> bf16 [N,K])
  transp_kernel<<<dim3(32,4,64),  TT, 0, stream>>>(Wq, wqkv,            1024,128,128,   8, 1048576,131072, 3145728,131072);
  transp_kernel<<<dim3(32,4,64),  TT, 0, stream>>>(Wk, wqkv + 1048576,  1024,128,128,   8, 1048576,131072, 3145728,131072);
  transp_kernel<<<dim3(32,4,64),  TT, 0, stream>>>(Wv, wqkv + 2097152,  1024,128,128,   8, 1048576,131072, 3145728,131072);
  transp_kernel<<<dim3(32,32,8),  TT, 0, stream>>>(Wproj, wpj,          1024,1024,1024, 1, 1048576,0, 1048576,0);
  transp_kernel<<<dim3(32,128,8), TT, 0, stream>>>(W1, w1t,             1024,4096,4096, 1, 4194304,0, 4194304,0);
  transp_kernel<<<dim3(128,32,8), TT, 0, stream>>>(W2, w2t,             4096,1024,1024, 1, 4194304,0, 4194304,0);
  transp_kernel<<<dim3(32,940,1), TT, 0, stream>>>(Whead, whd,          1024,30000,30080,1, 0,0, 0,0);

  embed_kernel<<<4096, TB, 0, stream>>>(x, tok_emb, pos_emb, hbuf);

  const float scale = 0.08838834764831845f;  // HS^-0.5
  for (int l = 0; l < 8; ++l){
    ln_kernel<<<4096, TB, 0, stream>>>(hbuf, ln1w + l*1024, ln1b + l*1024, xn);
    // QKV: [4096,1024] x [3072,1024]^T -> [4096,3072]
    gemm_bt<0><<<dim3(24,32,1), TB, 0, stream>>>(xn, wqkv + (size_t)l*3145728, qkvb, nullptr, nullptr,
        1024, 1024, 1024, 3072, 0, 1, 0,0, 0,0, 0,0);
    vtrans_kernel<<<dim3(16,4,64), TT, 0, stream>>>(qkvb, vT);
    // S = q k^T  (batched over bh): [512,128] x [512,128]^T -> bf16 [512,512]
    gemm_bt<0><<<dim3(4,4,64), TB, 0, stream>>>(qkvb, qkvb + 1024, spff, nullptr, nullptr,
        128, 3072, 3072, 512, 0, 8, 1572864,128, 1572864,128, 2097152,262144);
    softmax_kernel<<<dim3(512,64), TB, 0, stream>>>(spff, mask, scale);
    // att = P v : [512,512] x [128,512]^T -> [512,128] into concat layout
    gemm_bt<0><<<dim3(1,4,64), TB, 0, stream>>>(spff, vT, attb, nullptr, nullptr,
        512, 512, 512, 1024, 0, 8, 2097152,262144, 524288,65536, 524288,128);
    // h += att Wproj + bproj
    gemm_bt<2><<<dim3(8,32,1), TB, 0, stream>>>(attb, wpj + (size_t)l*1048576, nullptr, hbuf, bproj + l*1024,
        1024, 1024, 1024, 1024, 0, 1, 0,0, 0,0, 0,0);
    ln_kernel<<<4096, TB, 0, stream>>>(hbuf, ln2w + l*1024, ln2b + l*1024, xn);
    // ff = relu(xn W1 + b1): [4096,1024] x [4096,1024]^T -> [4096,4096]
    gemm_bt<1><<<dim3(32,32,1), TB, 0, stream>>>(xn, w1t + (size_t)l*4194304, spff, nullptr, b1 + l*4096,
        1024, 1024, 1024, 4096, 0, 1, 0,0, 0,0, 0,0);
    // h += ff W2 + b2
    gemm_bt<2><<<dim3(8,32,1), TB, 0, stream>>>(spff, w2t + (size_t)l*4194304, nullptr, hbuf, b2 + l*1024,
        4096, 4096, 4096, 1024, 0, 1, 0,0, 0,0, 0,0);
  }
  ln_kernel<<<4096, TB, 0, stream>>>(hbuf, lnfw, lnfb, xn);
  // logits = xn Whead^T + bhead  (N padded to 30080, stores guarded to 30000)
  gemm_bt<3><<<dim3(235,32,1), TB, 0, stream>>>(xn, whd, nullptr, logits, bhead,
      1024, 1024, 1024, 30000, 30000, 1, 0,0, 0,0, 0,0);
  loss_row_kernel<<<4096, TB, 0, stream>>>(logits, targets, mask, nllb);
  loss_final_kernel<<<1, TB, 0, stream>>>(nllb, mask, loss);
}